// Round 8
// baseline (344.641 us; speedup 1.0000x reference)
//
#include <hip/hip_runtime.h>

#define S_LEN 2048
#define DIMSZ 3072
#define NHEAD 24
#define HDIM 128
#define NQKV 9216
#define QSCALE 0.08838834764831845f
#define FMAX 12.0f

typedef unsigned short u16;
typedef unsigned int u32;
typedef __attribute__((ext_vector_type(8))) short short8;
typedef __attribute__((ext_vector_type(4))) float f32x4;

__device__ __forceinline__ u16 f2bf(float f) {
    u32 u = __float_as_uint(f);
    u32 r = (u + 0x7fffu + ((u >> 16) & 1u)) >> 16;
    return (u16)r;
}
__device__ __forceinline__ float bf2f(u16 u) {
    return __uint_as_float((u32)u << 16);
}

__device__ __forceinline__ void lds16(u16* lds, const u16* g) {
    __builtin_amdgcn_global_load_lds((const __attribute__((address_space(1))) u32*)g,
                                     (__attribute__((address_space(3))) u32*)lds, 16, 0, 0);
}

// ---------------- conversion kernels ----------------
__global__ void k_f2bf4(const float4* __restrict__ src, u16* __restrict__ dst, int n4) {
    int i = blockIdx.x * blockDim.x + threadIdx.x;
    if (i >= n4) return;
    float4 v = src[i];
    u32 lo = (u32)f2bf(v.x) | ((u32)f2bf(v.y) << 16);
    u32 hi = (u32)f2bf(v.z) | ((u32)f2bf(v.w) << 16);
    uint2 p; p.x = lo; p.y = hi;
    *(uint2*)(dst + (size_t)i * 4) = p;
}

// ---------------- QKV GEMM: C[m][n] = sum_k A[m][k]*W[n][k], C bf16 ----------------
// Tile 128x192, BK=32, grid 16x48 = 768 = 3 blocks/CU of equal work.
// REGISTER-PIPELINED fragments: frags(T+1) ds_reads issued BEFORE MFMA(T), waited
// (lgkmcnt 0) only at top of iter T+1 -> LDS-read pipe drains under the MFMA cluster,
// breaking the read-phase/MFMA-phase serialization measured in r6/r7 (MfmaUtil 38%).
// Stage T+2 into the dead buffer right after the lgkm+barrier; counted vmcnt(5).
__global__ __launch_bounds__(256, 2) void k_gemm(const u16* __restrict__ A, const u16* __restrict__ W,
                                                 u16* __restrict__ C) {
    __shared__ __align__(16) u16 As[2][128 * 32]; // 8 KB each
    __shared__ __align__(16) u16 Bs[2][192 * 32]; // 12 KB each
    const int tid = threadIdx.x, wave = tid >> 6, lane = tid & 63;
    const int bm = blockIdx.x / 48, bn = blockIdx.x % 48;
    const int wm = wave >> 1, wn = wave & 1; // 2M x 2N
    const int frow = lane & 15, fk = lane >> 4;
    const u16* baseA = A + (size_t)(bm * 128) * DIMSZ;
    const u16* baseW = W + (size_t)(bn * 192) * DIMSZ;

    auto stage = [&](int b, int kt) { // A: 2 loads, B: 3 loads per thread
#pragma unroll
        for (int j = 0; j < 2; ++j) {
            int flat = j * 256 + tid, row = flat >> 2, ch = flat & 3;
            lds16(&As[b][flat * 8], baseA + (size_t)row * DIMSZ + kt * 32 + ((ch ^ ((row >> 1) & 3)) * 8));
        }
#pragma unroll
        for (int j = 0; j < 3; ++j) {
            int flat = j * 256 + tid, row = flat >> 2, ch = flat & 3;
            lds16(&Bs[b][flat * 8], baseW + (size_t)row * DIMSZ + kt * 32 + ((ch ^ ((row >> 1) & 3)) * 8));
        }
    };

#define FRAG_READ(af_, bf_, LA_, LB_)                                                    \
    _Pragma("unroll") for (int mf = 0; mf < 4; ++mf) {                                   \
        int row = wm * 64 + mf * 16 + frow;                                              \
        af_[mf] = *(const short8*)&LA_[row * 32 + ((fk ^ ((row >> 1) & 3)) * 8)];        \
    }                                                                                    \
    _Pragma("unroll") for (int nf = 0; nf < 6; ++nf) {                                   \
        int row = wn * 96 + nf * 16 + frow;                                              \
        bf_[nf] = *(const short8*)&LB_[row * 32 + ((fk ^ ((row >> 1) & 3)) * 8)];        \
    }

    // prologue: stage tiles 0,1; read frags(0)
    stage(0, 0); stage(1, 1);
    asm volatile("s_waitcnt vmcnt(5)"); // tile 0 landed
    __builtin_amdgcn_s_barrier();

    f32x4 acc[4][6] = {};
    short8 afA[4], bfA[6], afB[4], bfB[6];
    FRAG_READ(afA, bfA, As[0], Bs[0])

#define GBODY(T, afC, bfC, afN, bfN)                                                     \
    {                                                                                    \
        const int b_ = (T) & 1;                                                          \
        asm volatile("s_waitcnt lgkmcnt(0)"); /* frags(T) in regs; buf[b_] dead */       \
        __builtin_amdgcn_s_barrier();         /* all waves done reading buf[b_] */       \
        if ((T) < 94) {                                                                  \
            stage(b_, (T) + 2);               /* overwrite dead buffer */                \
            asm volatile("s_waitcnt vmcnt(5)"); /* tile T+1's 5 loads landed */          \
        } else if ((T) == 94) {                                                          \
            asm volatile("s_waitcnt vmcnt(0)");                                          \
        }                                                                                \
        __builtin_amdgcn_s_barrier();         /* tile T+1 globally visible */            \
        if ((T) < 95) { FRAG_READ(afN, bfN, As[b_ ^ 1], Bs[b_ ^ 1]) }                    \
        __builtin_amdgcn_s_setprio(1);                                                   \
        _Pragma("unroll") for (int mf = 0; mf < 4; ++mf)                                 \
            _Pragma("unroll") for (int nf = 0; nf < 6; ++nf)                             \
                acc[mf][nf] = __builtin_amdgcn_mfma_f32_16x16x32_bf16(                   \
                    afC[mf], bfC[nf], acc[mf][nf], 0, 0, 0);                             \
        __builtin_amdgcn_s_setprio(0);                                                   \
    }

    for (int T = 0; T < 96; T += 2) {
        GBODY(T, afA, bfA, afB, bfB)
        GBODY(T + 1, afB, bfB, afA, bfA)
    }
#undef GBODY
#undef FRAG_READ

    // epilogue: bf16 C
#pragma unroll
    for (int mf = 0; mf < 4; ++mf) {
#pragma unroll
        for (int nf = 0; nf < 6; ++nf) {
            int n = bn * 192 + wn * 96 + nf * 16 + frow;
#pragma unroll
            for (int i = 0; i < 4; ++i) {
                int m = bm * 128 + wm * 64 + mf * 16 + fk * 4 + i;
                C[(size_t)m * NQKV + n] = f2bf(acc[mf][nf][i]);
            }
        }
    }
}

// ---------------- postprocess: bias + RMSNorm + RoPE + layout (reads bf16 qkv) --------
__global__ void k_post(const u16* __restrict__ qkv, const float* __restrict__ nw_q,
                       const float* __restrict__ nw_k, const float* __restrict__ bq,
                       const float* __restrict__ bk, const float* __restrict__ bv,
                       const float* __restrict__ cosT, const float* __restrict__ sinT,
                       u16* __restrict__ Qb, u16* __restrict__ Kb, u16* __restrict__ Vt) {
    const int wave = threadIdx.x >> 6, lane = threadIdx.x & 63;
    const int s = blockIdx.x * 4 + wave;
    const int h = blockIdx.y;
    const int d0 = 2 * lane, d1 = 2 * lane + 1;
    const float c = cosT[s * HDIM + d0], sn = sinT[s * HDIM + d0];
    const u16* r0 = qkv + (size_t)s * NQKV + h * HDIM;
    // Q
    {
        float x0 = bf2f(r0[d0]) + bq[h * HDIM + d0];
        float x1 = bf2f(r0[d1]) + bq[h * HDIM + d1];
        float ss = x0 * x0 + x1 * x1;
        for (int m = 1; m < 64; m <<= 1) ss += __shfl_xor(ss, m);
        float r = rsqrtf(ss * (1.0f / 128.0f) + 1e-6f);
        x0 *= r * nw_q[d0]; x1 *= r * nw_q[d1];
        float o0 = (x0 * c - x1 * sn) * QSCALE;
        float o1 = (x1 * c + x0 * sn) * QSCALE;
        u32 p = (u32)f2bf(o0) | ((u32)f2bf(o1) << 16);
        *(u32*)&Qb[((size_t)h * S_LEN + s) * HDIM + d0] = p;
    }
    // K
    {
        float x0 = bf2f(r0[3072 + d0]) + bk[h * HDIM + d0];
        float x1 = bf2f(r0[3072 + d1]) + bk[h * HDIM + d1];
        float ss = x0 * x0 + x1 * x1;
        for (int m = 1; m < 64; m <<= 1) ss += __shfl_xor(ss, m);
        float r = rsqrtf(ss * (1.0f / 128.0f) + 1e-6f);
        x0 *= r * nw_k[d0]; x1 *= r * nw_k[d1];
        float o0 = x0 * c - x1 * sn;
        float o1 = x1 * c + x0 * sn;
        u32 p = (u32)f2bf(o0) | ((u32)f2bf(o1) << 16);
        *(u32*)&Kb[((size_t)h * S_LEN + s) * HDIM + d0] = p;
    }
    // V (transposed)
    {
        float v0 = bf2f(r0[6144 + d0]) + bv[h * HDIM + d0];
        float v1 = bf2f(r0[6144 + d1]) + bv[h * HDIM + d1];
        Vt[((size_t)h * HDIM + d0) * S_LEN + s] = f2bf(v0);
        Vt[((size_t)h * HDIM + d1) * S_LEN + s] = f2bf(v1);
    }
}

// ---------------- flash attention (no mask, fixed-max softmax) ----------------
__global__ __launch_bounds__(256, 2) void k_attn(const u16* __restrict__ Qb, const u16* __restrict__ Kb,
                                                 const u16* __restrict__ Vt, float* __restrict__ out) {
    __shared__ __align__(16) u16 Ks[2][64 * 128];   // [key][d], chunk ^= row&15
    __shared__ __align__(16) u16 Vs[2][128 * 64];   // [d][key], chunk ^= row&7
    __shared__ __align__(16) u16 Ps[4][32 * 64];    // per-wave P, chunk ^= row&7
    const int wave = threadIdx.x >> 6, lane = threadIdx.x & 63;
    const int wg = (blockIdx.x & 7) * 48 + (blockIdx.x >> 3);
    const int h = wg >> 4, qb = wg & 15;
    const int frow = lane & 15, fk = lane >> 4;

    short8 qf[2][4];
#pragma unroll
    for (int qg = 0; qg < 2; ++qg) {
        const u16* qbase = Qb + ((size_t)h * S_LEN + qb * 128 + wave * 32 + qg * 16 + frow) * HDIM + fk * 8;
#pragma unroll
        for (int ks = 0; ks < 4; ++ks) qf[qg][ks] = *(const short8*)(qbase + ks * 32);
    }

    f32x4 o[2][8] = {};
    float l_p[2][4] = {};

#define STAGE(buf, kt)                                                                       \
    {                                                                                        \
        _Pragma("unroll") for (int c = 0; c < 4; ++c) {                                      \
            int fi = (wave * 4 + c) * 64 + lane;                                             \
            {                                                                                \
                int r = fi >> 4, ch = fi & 15;                                               \
                lds16(Ks[buf] + (wave * 4 + c) * 512,                                        \
                      Kb + ((size_t)h * S_LEN + (kt) * 64 + r) * HDIM + ((ch ^ (r & 15)) * 8)); \
            }                                                                                \
            {                                                                                \
                int r = fi >> 3, ch = fi & 7;                                                \
                lds16(Vs[buf] + (wave * 4 + c) * 512,                                        \
                      Vt + ((size_t)h * HDIM + r) * S_LEN + (kt) * 64 + ((ch ^ (r & 7)) * 8)); \
            }                                                                                \
        }                                                                                    \
    }

    STAGE(0, 0);
    __syncthreads();
    int cur = 0;

    for (int kt = 0; kt < S_LEN / 64; ++kt) {
        if (kt + 1 < S_LEN / 64) STAGE(cur ^ 1, kt + 1);
        f32x4 sacc[2][4] = {};
#pragma unroll
        for (int nf = 0; nf < 4; ++nf) {
#pragma unroll
            for (int ks = 0; ks < 4; ++ks) {
                short8 kf = *(const short8*)&Ks[cur][(nf * 16 + frow) * 128 + (((ks * 4 + fk) ^ frow) & 15) * 8];
#pragma unroll
                for (int qg = 0; qg < 2; ++qg)
                    sacc[qg][nf] = __builtin_amdgcn_mfma_f32_16x16x32_bf16(qf[qg][ks], kf, sacc[qg][nf], 0, 0, 0);
            }
        }
#pragma unroll
        for (int qg = 0; qg < 2; ++qg)
#pragma unroll
            for (int nf = 0; nf < 4; ++nf)
#pragma unroll
                for (int i = 0; i < 4; ++i) {
                    float p = __expf(sacc[qg][nf][i] - FMAX);
                    l_p[qg][i] += p;
                    int row = qg * 16 + fk * 4 + i, col = nf * 16 + frow;
                    Ps[wave][row * 64 + (((col >> 3) ^ (row & 7)) << 3) + (col & 7)] = f2bf(p);
                }
#pragma unroll
        for (int ks = 0; ks < 2; ++ks) {
            short8 pf[2];
#pragma unroll
            for (int qg = 0; qg < 2; ++qg)
                pf[qg] = *(const short8*)&Ps[wave][(qg * 16 + frow) * 64 + (((ks * 4 + fk) ^ (frow & 7)) & 7) * 8];
#pragma unroll
            for (int nf8 = 0; nf8 < 8; ++nf8) {
                short8 vf = *(const short8*)&Vs[cur][(nf8 * 16 + frow) * 64 + (((ks * 4 + fk) ^ (frow & 7)) & 7) * 8];
#pragma unroll
                for (int qg = 0; qg < 2; ++qg)
                    o[qg][nf8] = __builtin_amdgcn_mfma_f32_16x16x32_bf16(pf[qg], vf, o[qg][nf8], 0, 0, 0);
            }
        }
        __syncthreads();
        cur ^= 1;
    }
#undef STAGE

#pragma unroll
    for (int msk = 1; msk < 16; msk <<= 1)
#pragma unroll
        for (int qg = 0; qg < 2; ++qg)
#pragma unroll
            for (int i = 0; i < 4; ++i) l_p[qg][i] += __shfl_xor(l_p[qg][i], msk);

#pragma unroll
    for (int qg = 0; qg < 2; ++qg)
#pragma unroll
        for (int nf8 = 0; nf8 < 8; ++nf8)
#pragma unroll
            for (int i = 0; i < 4; ++i) {
                int srow = qb * 128 + wave * 32 + qg * 16 + fk * 4 + i;
                out[(size_t)srow * DIMSZ + h * HDIM + nf8 * 16 + frow] = o[qg][nf8][i] / l_p[qg][i];
            }
}

// ---------------- launch ----------------
extern "C" void kernel_launch(void* const* d_in, const int* in_sizes, int n_in,
                              void* d_out, int out_size, void* d_ws, size_t ws_size,
                              hipStream_t stream) {
    const float* hs = (const float*)d_in[0];
    const float* wq = (const float*)d_in[1];
    const float* bq = (const float*)d_in[2];
    const float* wk = (const float*)d_in[3];
    const float* bk = (const float*)d_in[4];
    const float* wv = (const float*)d_in[5];
    const float* bv = (const float*)d_in[6];
    const float* nq = (const float*)d_in[7];
    const float* nk = (const float*)d_in[8];
    const float* cosT = (const float*)d_in[9];
    const float* sinT = (const float*)d_in[10];
    float* out = (float*)d_out;

    char* ws = (char*)d_ws;
    u16* hs_b = (u16*)(ws);                      // 12,582,912
    u16* w_b = (u16*)(ws + 12582912);            // 56,623,104
    u16* qkv = (u16*)(ws + 69206016);            // 37,748,736
    u16* Qb = (u16*)(ws + 106954752);            // 12,582,912
    u16* Kb = (u16*)(ws + 119537664);            // 12,582,912
    u16* Vt = (u16*)(ws + 132120576);            // 12,582,912 -> total 144,703,488 B

    k_f2bf4<<<6144, 256, 0, stream>>>((const float4*)hs, hs_b, 1572864);
    k_f2bf4<<<9216, 256, 0, stream>>>((const float4*)wq, w_b, 2359296);
    k_f2bf4<<<9216, 256, 0, stream>>>((const float4*)wk, w_b + 9437184, 2359296);
    k_f2bf4<<<9216, 256, 0, stream>>>((const float4*)wv, w_b + 18874368, 2359296);

    // QKV projection: 768 blocks (16 bm x 48 bn), 3 blocks/CU of equal work
    k_gemm<<<dim3(768), 256, 0, stream>>>(hs_b, w_b, qkv);

    k_post<<<dim3(512, 24), 256, 0, stream>>>(qkv, nq, nk, bq, bk, bv, cosT, sinT, Qb, Kb, Vt);

    // attention: 384 blocks (16 qb x 24 heads), XCD-swizzled, monolithic
    k_attn<<<dim3(384), 256, 0, stream>>>(Qb, Kb, Vt, out);
}

// Round 9
// 300.431 us; speedup vs baseline: 1.1472x; 1.1472x over previous
//
#include <hip/hip_runtime.h>

#define S_LEN 2048
#define DIMSZ 3072
#define NHEAD 24
#define HDIM 128
#define NQKV 9216
#define QSCALE 0.08838834764831845f
#define FMAX 12.0f

typedef unsigned short u16;
typedef unsigned int u32;
typedef __attribute__((ext_vector_type(8))) short short8;
typedef __attribute__((ext_vector_type(4))) float f32x4;

__device__ __forceinline__ u16 f2bf(float f) {
    u32 u = __float_as_uint(f);
    u32 r = (u + 0x7fffu + ((u >> 16) & 1u)) >> 16;
    return (u16)r;
}
__device__ __forceinline__ float bf2f(u16 u) {
    return __uint_as_float((u32)u << 16);
}

__device__ __forceinline__ void lds16(u16* lds, const u16* g) {
    __builtin_amdgcn_global_load_lds((const __attribute__((address_space(1))) u32*)g,
                                     (__attribute__((address_space(3))) u32*)lds, 16, 0, 0);
}

// ---------------- merged conversion kernel (hs, wq, wk, wv -> bf16) ----------------
__global__ void k_conv(const float4* __restrict__ hs, const float4* __restrict__ wq,
                       const float4* __restrict__ wk, const float4* __restrict__ wv,
                       u16* __restrict__ hs_b, u16* __restrict__ w_b) {
    int i = blockIdx.x * 256 + threadIdx.x;
    const float4* src;
    u16* dst;
    if (i < 1572864) { src = hs + i; dst = hs_b + (size_t)i * 4; }
    else if (i < 3932160) { src = wq + (i - 1572864); dst = w_b + (size_t)(i - 1572864) * 4; }
    else if (i < 6291456) { src = wk + (i - 3932160); dst = w_b + 9437184 + (size_t)(i - 3932160) * 4; }
    else { src = wv + (i - 6291456); dst = w_b + 18874368 + (size_t)(i - 6291456) * 4; }
    float4 v = *src;
    u32 lo = (u32)f2bf(v.x) | ((u32)f2bf(v.y) << 16);
    u32 hi = (u32)f2bf(v.z) | ((u32)f2bf(v.w) << 16);
    uint2 p; p.x = lo; p.y = hi;
    *(uint2*)dst = p;
}

// ---------------- QKV GEMM (r6 proven): tile 256x144, BK=32, grid 8x64=512, 2/CU ------
__global__ __launch_bounds__(256, 2) void k_gemm(const u16* __restrict__ A, const u16* __restrict__ W,
                                                 u16* __restrict__ C) {
    __shared__ __align__(16) u16 As[2][256 * 32]; // 16 KB each
    __shared__ __align__(16) u16 Bs[2][192 * 32]; // 12 KB each (rows 144-191 = pad)
    const int tid = threadIdx.x, wave = tid >> 6, lane = tid & 63;
    const int bm = blockIdx.x & 7, bn = blockIdx.x >> 3;
    const int frow = lane & 15, fk = lane >> 4;
    const u16* baseA = A + (size_t)(bm * 256) * DIMSZ;

    auto stageA = [&](int b, int kt) {
#pragma unroll
        for (int j = 0; j < 4; ++j) {
            int flat = j * 256 + tid, row = flat >> 2, ch = flat & 3;
            lds16(&As[b][flat * 8], baseA + (size_t)row * DIMSZ + kt * 32 + ((ch ^ ((row >> 1) & 3)) * 8));
        }
    };
    auto stageB = [&](int b, int kt) {
#pragma unroll
        for (int j = 0; j < 3; ++j) {
            int flat = j * 256 + tid, row = flat >> 2, ch = flat & 3;
            int srow = bn * 144 + row;
            srow = (srow > NQKV - 1) ? (NQKV - 1) : srow;
            lds16(&Bs[b][flat * 8], W + (size_t)srow * DIMSZ + kt * 32 + ((ch ^ ((row >> 1) & 3)) * 8));
        }
    };

    stageA(0, 0); stageB(0, 0); stageA(1, 1); stageB(1, 1);
    asm volatile("s_waitcnt vmcnt(7)");
    __builtin_amdgcn_s_barrier();

    f32x4 acc[4][9] = {};
    for (int T = 0; T < 96; ++T) {
        const int b = T & 1;
        const u16* LA = As[b];
        const u16* LB = Bs[b];
        short8 af[4], bf[9];
#pragma unroll
        for (int mf = 0; mf < 4; ++mf) {
            int row = wave * 64 + mf * 16 + frow;
            af[mf] = *(const short8*)&LA[row * 32 + ((fk ^ ((row >> 1) & 3)) * 8)];
        }
#pragma unroll
        for (int nf = 0; nf < 9; ++nf) {
            int row = nf * 16 + frow;
            bf[nf] = *(const short8*)&LB[row * 32 + ((fk ^ ((row >> 1) & 3)) * 8)];
        }
        __builtin_amdgcn_s_barrier();
        __builtin_amdgcn_s_setprio(1);
#pragma unroll
        for (int mf = 0; mf < 4; ++mf)
#pragma unroll
            for (int nf = 0; nf < 9; ++nf)
                acc[mf][nf] = __builtin_amdgcn_mfma_f32_16x16x32_bf16(af[mf], bf[nf], acc[mf][nf], 0, 0, 0);
        __builtin_amdgcn_s_setprio(0);
        __builtin_amdgcn_s_barrier();
        if (T < 94) {
            stageA(b, T + 2); stageB(b, T + 2);
            asm volatile("s_waitcnt vmcnt(7)");
            __builtin_amdgcn_s_barrier();
        } else if (T == 94) {
            asm volatile("s_waitcnt vmcnt(0)");
            __builtin_amdgcn_s_barrier();
        }
    }

    // epilogue: wave owns rows wave*64..+63; block cols bn*144..+143 (9 nf groups)
#pragma unroll
    for (int mf = 0; mf < 4; ++mf) {
#pragma unroll
        for (int nf = 0; nf < 9; ++nf) {
            int n = bn * 144 + nf * 16 + frow;
#pragma unroll
            for (int i = 0; i < 4; ++i) {
                int m = bm * 256 + wave * 64 + mf * 16 + fk * 4 + i;
                C[(size_t)m * NQKV + n] = f2bf(acc[mf][nf][i]);
            }
        }
    }
}

// ---------------- postprocess: bias + RMSNorm + RoPE + layout (reads bf16 qkv) --------
__global__ void k_post(const u16* __restrict__ qkv, const float* __restrict__ nw_q,
                       const float* __restrict__ nw_k, const float* __restrict__ bq,
                       const float* __restrict__ bk, const float* __restrict__ bv,
                       const float* __restrict__ cosT, const float* __restrict__ sinT,
                       u16* __restrict__ Qb, u16* __restrict__ Kb, u16* __restrict__ Vt) {
    const int wave = threadIdx.x >> 6, lane = threadIdx.x & 63;
    const int s = blockIdx.x * 4 + wave;
    const int h = blockIdx.y;
    const int d0 = 2 * lane, d1 = 2 * lane + 1;
    const float c = cosT[s * HDIM + d0], sn = sinT[s * HDIM + d0];
    const u16* r0 = qkv + (size_t)s * NQKV + h * HDIM;
    // Q
    {
        float x0 = bf2f(r0[d0]) + bq[h * HDIM + d0];
        float x1 = bf2f(r0[d1]) + bq[h * HDIM + d1];
        float ss = x0 * x0 + x1 * x1;
        for (int m = 1; m < 64; m <<= 1) ss += __shfl_xor(ss, m);
        float r = rsqrtf(ss * (1.0f / 128.0f) + 1e-6f);
        x0 *= r * nw_q[d0]; x1 *= r * nw_q[d1];
        float o0 = (x0 * c - x1 * sn) * QSCALE;
        float o1 = (x1 * c + x0 * sn) * QSCALE;
        u32 p = (u32)f2bf(o0) | ((u32)f2bf(o1) << 16);
        *(u32*)&Qb[((size_t)h * S_LEN + s) * HDIM + d0] = p;
    }
    // K
    {
        float x0 = bf2f(r0[3072 + d0]) + bk[h * HDIM + d0];
        float x1 = bf2f(r0[3072 + d1]) + bk[h * HDIM + d1];
        float ss = x0 * x0 + x1 * x1;
        for (int m = 1; m < 64; m <<= 1) ss += __shfl_xor(ss, m);
        float r = rsqrtf(ss * (1.0f / 128.0f) + 1e-6f);
        x0 *= r * nw_k[d0]; x1 *= r * nw_k[d1];
        float o0 = x0 * c - x1 * sn;
        float o1 = x1 * c + x0 * sn;
        u32 p = (u32)f2bf(o0) | ((u32)f2bf(o1) << 16);
        *(u32*)&Kb[((size_t)h * S_LEN + s) * HDIM + d0] = p;
    }
    // V (transposed)
    {
        float v0 = bf2f(r0[6144 + d0]) + bv[h * HDIM + d0];
        float v1 = bf2f(r0[6144 + d1]) + bv[h * HDIM + d1];
        Vt[((size_t)h * HDIM + d0) * S_LEN + s] = f2bf(v0);
        Vt[((size_t)h * HDIM + d1) * S_LEN + s] = f2bf(v1);
    }
}

// ---------------- flash attention (swapped-operand QK^T, fixed-max softmax) ----------
__global__ __launch_bounds__(256, 2) void k_attn(const u16* __restrict__ Qb, const u16* __restrict__ Kb,
                                                 const u16* __restrict__ Vt, float* __restrict__ out) {
    __shared__ __align__(16) u16 Ks[2][64 * 128];   // [key][d], chunk ^= row&15
    __shared__ __align__(16) u16 Vs[2][128 * 64];   // [d][key], chunk ^= row&7
    __shared__ __align__(16) u16 Ps[4][32 * 64];    // per-wave P [q][key], 16B-chunk ^= row&7
    const int wave = threadIdx.x >> 6, lane = threadIdx.x & 63;
    const int wg = (blockIdx.x & 7) * 48 + (blockIdx.x >> 3);
    const int h = wg >> 4, qb = wg & 15;
    const int frow = lane & 15, fk = lane >> 4;

    short8 qf[2][4];
#pragma unroll
    for (int qg = 0; qg < 2; ++qg) {
        const u16* qbase = Qb + ((size_t)h * S_LEN + qb * 128 + wave * 32 + qg * 16 + frow) * HDIM + fk * 8;
#pragma unroll
        for (int ks = 0; ks < 4; ++ks) qf[qg][ks] = *(const short8*)(qbase + ks * 32);
    }

    f32x4 o[2][8] = {};
    float l_p[2] = {0.f, 0.f};

#define STAGE(buf, kt)                                                                       \
    {                                                                                        \
        _Pragma("unroll") for (int c = 0; c < 4; ++c) {                                      \
            int fi = (wave * 4 + c) * 64 + lane;                                             \
            {                                                                                \
                int r = fi >> 4, ch = fi & 15;                                               \
                lds16(Ks[buf] + (wave * 4 + c) * 512,                                        \
                      Kb + ((size_t)h * S_LEN + (kt) * 64 + r) * HDIM + ((ch ^ (r & 15)) * 8)); \
            }                                                                                \
            {                                                                                \
                int r = fi >> 3, ch = fi & 7;                                                \
                lds16(Vs[buf] + (wave * 4 + c) * 512,                                        \
                      Vt + ((size_t)h * HDIM + r) * S_LEN + (kt) * 64 + ((ch ^ (r & 7)) * 8)); \
            }                                                                                \
        }                                                                                    \
    }

    STAGE(0, 0);
    __syncthreads();
    int cur = 0;

    for (int kt = 0; kt < S_LEN / 64; ++kt) {
        if (kt + 1 < S_LEN / 64) STAGE(cur ^ 1, kt + 1);
        // S^T = K Q^T : A = K-rows, B = Q-rows
        f32x4 sacc[2][4] = {};
#pragma unroll
        for (int nf = 0; nf < 4; ++nf) {
#pragma unroll
            for (int ks = 0; ks < 4; ++ks) {
                short8 kf = *(const short8*)&Ks[cur][(nf * 16 + frow) * 128 + (((ks * 4 + fk) ^ frow) & 15) * 8];
#pragma unroll
                for (int qg = 0; qg < 2; ++qg)
                    sacc[qg][nf] = __builtin_amdgcn_mfma_f32_16x16x32_bf16(kf, qf[qg][ks], sacc[qg][nf], 0, 0, 0);
            }
        }
        // fixed-max softmax; lane owns q-row (qg*16+frow), keys nf*16+fk*4+{0..3}
#pragma unroll
        for (int qg = 0; qg < 2; ++qg) {
            int prow = qg * 16 + frow;
#pragma unroll
            for (int nf = 0; nf < 4; ++nf) {
                float p0 = __expf(sacc[qg][nf][0] - FMAX);
                float p1 = __expf(sacc[qg][nf][1] - FMAX);
                float p2 = __expf(sacc[qg][nf][2] - FMAX);
                float p3 = __expf(sacc[qg][nf][3] - FMAX);
                l_p[qg] += (p0 + p1) + (p2 + p3);
                uint2 pk;
                pk.x = (u32)f2bf(p0) | ((u32)f2bf(p1) << 16);
                pk.y = (u32)f2bf(p2) | ((u32)f2bf(p3) << 16);
                int c16 = (nf * 2 + (fk >> 1)) ^ (prow & 7); // 16B-chunk swizzle, matches pf read
                *(uint2*)&Ps[wave][prow * 64 + c16 * 8 + (fk & 1) * 4] = pk;
            }
        }
        // O += P V  (pf read layout identical to pre-swap)
#pragma unroll
        for (int ks = 0; ks < 2; ++ks) {
            short8 pf[2];
#pragma unroll
            for (int qg = 0; qg < 2; ++qg)
                pf[qg] = *(const short8*)&Ps[wave][(qg * 16 + frow) * 64 + (((ks * 4 + fk) ^ (frow & 7)) & 7) * 8];
#pragma unroll
            for (int nf8 = 0; nf8 < 8; ++nf8) {
                short8 vf = *(const short8*)&Vs[cur][(nf8 * 16 + frow) * 64 + (((ks * 4 + fk) ^ (frow & 7)) & 7) * 8];
#pragma unroll
                for (int qg = 0; qg < 2; ++qg)
                    o[qg][nf8] = __builtin_amdgcn_mfma_f32_16x16x32_bf16(pf[qg], vf, o[qg][nf8], 0, 0, 0);
            }
        }
        __syncthreads();
        cur ^= 1;
    }
#undef STAGE

    // l: sum the 4 fk-group partials (lanes sharing frow)
#pragma unroll
    for (int qg = 0; qg < 2; ++qg) {
        l_p[qg] += __shfl_xor(l_p[qg], 16);
        l_p[qg] += __shfl_xor(l_p[qg], 32);
    }

#pragma unroll
    for (int qg = 0; qg < 2; ++qg)
#pragma unroll
        for (int i = 0; i < 4; ++i) {
            float rinv = 1.0f / __shfl(l_p[qg], fk * 4 + i);
            int srow = qb * 128 + wave * 32 + qg * 16 + fk * 4 + i;
#pragma unroll
            for (int nf8 = 0; nf8 < 8; ++nf8)
                out[(size_t)srow * DIMSZ + h * HDIM + nf8 * 16 + frow] = o[qg][nf8][i] * rinv;
        }
}

// ---------------- launch ----------------
extern "C" void kernel_launch(void* const* d_in, const int* in_sizes, int n_in,
                              void* d_out, int out_size, void* d_ws, size_t ws_size,
                              hipStream_t stream) {
    const float* hs = (const float*)d_in[0];
    const float* wq = (const float*)d_in[1];
    const float* bq = (const float*)d_in[2];
    const float* wk = (const float*)d_in[3];
    const float* bk = (const float*)d_in[4];
    const float* wv = (const float*)d_in[5];
    const float* bv = (const float*)d_in[6];
    const float* nq = (const float*)d_in[7];
    const float* nk = (const float*)d_in[8];
    const float* cosT = (const float*)d_in[9];
    const float* sinT = (const float*)d_in[10];
    float* out = (float*)d_out;

    char* ws = (char*)d_ws;
    u16* hs_b = (u16*)(ws);                      // 12,582,912
    u16* w_b = (u16*)(ws + 12582912);            // 56,623,104
    u16* qkv = (u16*)(ws + 69206016);            // 37,748,736
    u16* Qb = (u16*)(ws + 106954752);            // 12,582,912
    u16* Kb = (u16*)(ws + 119537664);            // 12,582,912
    u16* Vt = (u16*)(ws + 132120576);            // 12,582,912 -> total 144,703,488 B

    k_conv<<<dim3(33792), 256, 0, stream>>>((const float4*)hs, (const float4*)wq,
                                            (const float4*)wk, (const float4*)wv, hs_b, w_b);

    k_gemm<<<dim3(512), 256, 0, stream>>>(hs_b, w_b, qkv);

    k_post<<<dim3(512, 24), 256, 0, stream>>>(qkv, nq, nk, bq, bk, bv, cosT, sinT, Qb, Kb, Vt);

    k_attn<<<dim3(384), 256, 0, stream>>>(Qb, Kb, Vt, out);
}

// Round 10
// 292.098 us; speedup vs baseline: 1.1799x; 1.0285x over previous
//
#include <hip/hip_runtime.h>

#define S_LEN 2048
#define DIMSZ 3072
#define NHEAD 24
#define HDIM 128
#define NQKV 9216
#define QSCALE 0.08838834764831845f
#define FMAX 12.0f

typedef unsigned short u16;
typedef unsigned int u32;
typedef __attribute__((ext_vector_type(8))) short short8;
typedef __attribute__((ext_vector_type(4))) float f32x4;

__device__ __forceinline__ u16 f2bf(float f) {
    u32 u = __float_as_uint(f);
    u32 r = (u + 0x7fffu + ((u >> 16) & 1u)) >> 16;
    return (u16)r;
}
__device__ __forceinline__ float bf2f(u16 u) {
    return __uint_as_float((u32)u << 16);
}

__device__ __forceinline__ void lds16(u16* lds, const u16* g) {
    __builtin_amdgcn_global_load_lds((const __attribute__((address_space(1))) u32*)g,
                                     (__attribute__((address_space(3))) u32*)lds, 16, 0, 0);
}

// ---------------- merged conversion kernel (hs, wq, wk, wv -> bf16) ----------------
__global__ void k_conv(const float4* __restrict__ hs, const float4* __restrict__ wq,
                       const float4* __restrict__ wk, const float4* __restrict__ wv,
                       u16* __restrict__ hs_b, u16* __restrict__ w_b) {
    int i = blockIdx.x * 256 + threadIdx.x;
    const float4* src;
    u16* dst;
    if (i < 1572864) { src = hs + i; dst = hs_b + (size_t)i * 4; }
    else if (i < 3932160) { src = wq + (i - 1572864); dst = w_b + (size_t)(i - 1572864) * 4; }
    else if (i < 6291456) { src = wk + (i - 3932160); dst = w_b + 9437184 + (size_t)(i - 3932160) * 4; }
    else { src = wv + (i - 6291456); dst = w_b + 18874368 + (size_t)(i - 6291456) * 4; }
    float4 v = *src;
    u32 lo = (u32)f2bf(v.x) | ((u32)f2bf(v.y) << 16);
    u32 hi = (u32)f2bf(v.z) | ((u32)f2bf(v.w) << 16);
    uint2 p; p.x = lo; p.y = hi;
    *(uint2*)dst = p;
}

// ---------------- QKV GEMM (r6/r9 proven): tile 256x144, BK=32, grid 8x64=512, 2/CU ---
__global__ __launch_bounds__(256, 2) void k_gemm(const u16* __restrict__ A, const u16* __restrict__ W,
                                                 u16* __restrict__ C) {
    __shared__ __align__(16) u16 As[2][256 * 32]; // 16 KB each
    __shared__ __align__(16) u16 Bs[2][192 * 32]; // 12 KB each (rows 144-191 = pad)
    const int tid = threadIdx.x, wave = tid >> 6, lane = tid & 63;
    const int bm = blockIdx.x & 7, bn = blockIdx.x >> 3;
    const int frow = lane & 15, fk = lane >> 4;
    const u16* baseA = A + (size_t)(bm * 256) * DIMSZ;

    auto stageA = [&](int b, int kt) {
#pragma unroll
        for (int j = 0; j < 4; ++j) {
            int flat = j * 256 + tid, row = flat >> 2, ch = flat & 3;
            lds16(&As[b][flat * 8], baseA + (size_t)row * DIMSZ + kt * 32 + ((ch ^ ((row >> 1) & 3)) * 8));
        }
    };
    auto stageB = [&](int b, int kt) {
#pragma unroll
        for (int j = 0; j < 3; ++j) {
            int flat = j * 256 + tid, row = flat >> 2, ch = flat & 3;
            int srow = bn * 144 + row;
            srow = (srow > NQKV - 1) ? (NQKV - 1) : srow;
            lds16(&Bs[b][flat * 8], W + (size_t)srow * DIMSZ + kt * 32 + ((ch ^ ((row >> 1) & 3)) * 8));
        }
    };

    stageA(0, 0); stageB(0, 0); stageA(1, 1); stageB(1, 1);
    asm volatile("s_waitcnt vmcnt(7)");
    __builtin_amdgcn_s_barrier();

    f32x4 acc[4][9] = {};
    for (int T = 0; T < 96; ++T) {
        const int b = T & 1;
        const u16* LA = As[b];
        const u16* LB = Bs[b];
        short8 af[4], bf[9];
#pragma unroll
        for (int mf = 0; mf < 4; ++mf) {
            int row = wave * 64 + mf * 16 + frow;
            af[mf] = *(const short8*)&LA[row * 32 + ((fk ^ ((row >> 1) & 3)) * 8)];
        }
#pragma unroll
        for (int nf = 0; nf < 9; ++nf) {
            int row = nf * 16 + frow;
            bf[nf] = *(const short8*)&LB[row * 32 + ((fk ^ ((row >> 1) & 3)) * 8)];
        }
        __builtin_amdgcn_s_barrier();
        __builtin_amdgcn_s_setprio(1);
#pragma unroll
        for (int mf = 0; mf < 4; ++mf)
#pragma unroll
            for (int nf = 0; nf < 9; ++nf)
                acc[mf][nf] = __builtin_amdgcn_mfma_f32_16x16x32_bf16(af[mf], bf[nf], acc[mf][nf], 0, 0, 0);
        __builtin_amdgcn_s_setprio(0);
        __builtin_amdgcn_s_barrier();
        if (T < 94) {
            stageA(b, T + 2); stageB(b, T + 2);
            asm volatile("s_waitcnt vmcnt(7)");
            __builtin_amdgcn_s_barrier();
        } else if (T == 94) {
            asm volatile("s_waitcnt vmcnt(0)");
            __builtin_amdgcn_s_barrier();
        }
    }

#pragma unroll
    for (int mf = 0; mf < 4; ++mf) {
#pragma unroll
        for (int nf = 0; nf < 9; ++nf) {
            int n = bn * 144 + nf * 16 + frow;
#pragma unroll
            for (int i = 0; i < 4; ++i) {
                int m = bm * 256 + wave * 64 + mf * 16 + fk * 4 + i;
                C[(size_t)m * NQKV + n] = f2bf(acc[mf][nf][i]);
            }
        }
    }
}

// ---------------- postprocess (VECTORIZED): bias + RMSNorm + RoPE + layout ------------
// 16 lanes x 8 elems per (s,h) row; row = h*2048 + s; 3072 blocks x 256 thr.
__global__ void k_post(const u16* __restrict__ qkv, const float* __restrict__ nw_q,
                       const float* __restrict__ nw_k, const float* __restrict__ bq,
                       const float* __restrict__ bk, const float* __restrict__ bv,
                       const float* __restrict__ cosT, const float* __restrict__ sinT,
                       u16* __restrict__ Qb, u16* __restrict__ Kb, u16* __restrict__ Vt) {
    const int tid = threadIdx.x;
    const int row = blockIdx.x * 16 + (tid >> 4);
    const int lane16 = tid & 15;
    const int s = row & 2047, h = row >> 11;
    const int d0 = lane16 * 8;
    const u16* base = qkv + (size_t)s * NQKV + h * HDIM + d0;

    float cs[8], sn[8];
    *(float4*)&cs[0] = *(const float4*)&cosT[s * HDIM + d0];
    *(float4*)&cs[4] = *(const float4*)&cosT[s * HDIM + d0 + 4];
    *(float4*)&sn[0] = *(const float4*)&sinT[s * HDIM + d0];
    *(float4*)&sn[4] = *(const float4*)&sinT[s * HDIM + d0 + 4];

    // ---- Q ----
    {
        short8 raw = *(const short8*)base;
        float b[8];
        *(float4*)&b[0] = *(const float4*)&bq[h * HDIM + d0];
        *(float4*)&b[4] = *(const float4*)&bq[h * HDIM + d0 + 4];
        float x[8], ss = 0.f;
#pragma unroll
        for (int j = 0; j < 8; ++j) { x[j] = bf2f((u16)raw[j]) + b[j]; ss += x[j] * x[j]; }
#pragma unroll
        for (int m = 1; m < 16; m <<= 1) ss += __shfl_xor(ss, m);
        float r = rsqrtf(ss * (1.0f / 128.0f) + 1e-6f);
        float w[8];
        *(float4*)&w[0] = *(const float4*)&nw_q[d0];
        *(float4*)&w[4] = *(const float4*)&nw_q[d0 + 4];
        u32 pk[4];
#pragma unroll
        for (int jp = 0; jp < 4; ++jp) {
            float e = x[2 * jp] * r * w[2 * jp];
            float o = x[2 * jp + 1] * r * w[2 * jp + 1];
            float y0 = (e * cs[2 * jp] - o * sn[2 * jp]) * QSCALE;
            float y1 = (o * cs[2 * jp] + e * sn[2 * jp]) * QSCALE;
            pk[jp] = (u32)f2bf(y0) | ((u32)f2bf(y1) << 16);
        }
        uint4 v; v.x = pk[0]; v.y = pk[1]; v.z = pk[2]; v.w = pk[3];
        *(uint4*)&Qb[((size_t)h * S_LEN + s) * HDIM + d0] = v;
    }
    // ---- K ----
    {
        short8 raw = *(const short8*)(base + 3072);
        float b[8];
        *(float4*)&b[0] = *(const float4*)&bk[h * HDIM + d0];
        *(float4*)&b[4] = *(const float4*)&bk[h * HDIM + d0 + 4];
        float x[8], ss = 0.f;
#pragma unroll
        for (int j = 0; j < 8; ++j) { x[j] = bf2f((u16)raw[j]) + b[j]; ss += x[j] * x[j]; }
#pragma unroll
        for (int m = 1; m < 16; m <<= 1) ss += __shfl_xor(ss, m);
        float r = rsqrtf(ss * (1.0f / 128.0f) + 1e-6f);
        float w[8];
        *(float4*)&w[0] = *(const float4*)&nw_k[d0];
        *(float4*)&w[4] = *(const float4*)&nw_k[d0 + 4];
        u32 pk[4];
#pragma unroll
        for (int jp = 0; jp < 4; ++jp) {
            float e = x[2 * jp] * r * w[2 * jp];
            float o = x[2 * jp + 1] * r * w[2 * jp + 1];
            float y0 = e * cs[2 * jp] - o * sn[2 * jp];
            float y1 = o * cs[2 * jp] + e * sn[2 * jp];
            pk[jp] = (u32)f2bf(y0) | ((u32)f2bf(y1) << 16);
        }
        uint4 v; v.x = pk[0]; v.y = pk[1]; v.z = pk[2]; v.w = pk[3];
        *(uint4*)&Kb[((size_t)h * S_LEN + s) * HDIM + d0] = v;
    }
    // ---- V (transposed) ----
    {
        short8 raw = *(const short8*)(base + 6144);
        float b[8];
        *(float4*)&b[0] = *(const float4*)&bv[h * HDIM + d0];
        *(float4*)&b[4] = *(const float4*)&bv[h * HDIM + d0 + 4];
#pragma unroll
        for (int j = 0; j < 8; ++j)
            Vt[((size_t)h * HDIM + d0 + j) * S_LEN + s] = f2bf(bf2f((u16)raw[j]) + b[j]);
    }
}

// ---------------- flash attention: 768 blocks (3/CU exact), 2 waves, KVBLK=32 --------
// Swapped-operand QK^T, fixed-max softmax. LDS 36 KB. XCD swizzle: 96 blocks (3 heads)
// per XCD -> K/V L2-resident. Vs/Ps use (row>>2)&3 chunk swizzle -> 2-way (free) reads.
__global__ __launch_bounds__(128, 2) void k_attn(const u16* __restrict__ Qb, const u16* __restrict__ Kb,
                                                 const u16* __restrict__ Vt, float* __restrict__ out) {
    __shared__ __align__(16) u16 Ks[2][32 * 128];  // [key][d], 16B-chunk ^= key&15
    __shared__ __align__(16) u16 Vs[2][128 * 32];  // [d][key], 16B-chunk ^= (d>>2)&3
    __shared__ __align__(16) u16 Ps[2][32 * 32];   // per-wave P [q][key], chunk ^= (q>>2)&3
    const int tid = threadIdx.x;
    const int wave = tid >> 6, lane = tid & 63;
    const int wg = (blockIdx.x & 7) * 96 + (blockIdx.x >> 3); // XCD-major, bijective
    const int h = wg >> 5, qb = wg & 31;
    const int frow = lane & 15, fk = lane >> 4;

    short8 qf[2][4];
#pragma unroll
    for (int qg = 0; qg < 2; ++qg) {
        const u16* qbase = Qb + ((size_t)h * S_LEN + qb * 64 + wave * 32 + qg * 16 + frow) * HDIM + fk * 8;
#pragma unroll
        for (int ks = 0; ks < 4; ++ks) qf[qg][ks] = *(const short8*)(qbase + ks * 32);
    }

    f32x4 o[2][8] = {};
    float l_p[2] = {0.f, 0.f};

#define STAGE(buf, kt)                                                                        \
    {                                                                                         \
        _Pragma("unroll") for (int c = 0; c < 4; ++c) {                                       \
            int flat = c * 128 + tid;                                                         \
            int r = flat >> 4, ch = flat & 15;                                                \
            lds16(Ks[buf] + flat * 8,                                                         \
                  Kb + ((size_t)h * S_LEN + (kt) * 32 + r) * HDIM + ((ch ^ (r & 15)) * 8));   \
        }                                                                                     \
        _Pragma("unroll") for (int c = 0; c < 4; ++c) {                                       \
            int flat = c * 128 + tid;                                                         \
            int r = flat >> 2, ch = flat & 3;                                                 \
            lds16(Vs[buf] + flat * 8,                                                         \
                  Vt + ((size_t)h * HDIM + r) * S_LEN + (kt) * 32 + ((ch ^ ((r >> 2) & 3)) * 8)); \
        }                                                                                     \
    }

    STAGE(0, 0);
    __syncthreads();
    int cur = 0;

    for (int kt = 0; kt < 64; ++kt) {
        if (kt + 1 < 64) STAGE(cur ^ 1, kt + 1);
        // S^T = K Q^T : A = K-rows(keys), B = Q-rows
        f32x4 sacc[2][2] = {};
#pragma unroll
        for (int nf = 0; nf < 2; ++nf) {
#pragma unroll
            for (int ks = 0; ks < 4; ++ks) {
                short8 kf = *(const short8*)&Ks[cur][(nf * 16 + frow) * 128 + (((ks * 4 + fk) ^ frow) * 8)];
#pragma unroll
                for (int qg = 0; qg < 2; ++qg)
                    sacc[qg][nf] = __builtin_amdgcn_mfma_f32_16x16x32_bf16(kf, qf[qg][ks], sacc[qg][nf], 0, 0, 0);
            }
        }
        // fixed-max softmax: lane owns q-row qg*16+frow, keys nf*16+fk*4+{0..3}
#pragma unroll
        for (int qg = 0; qg < 2; ++qg) {
            int prow = qg * 16 + frow;
#pragma unroll
            for (int nf = 0; nf < 2; ++nf) {
                float p0 = __expf(sacc[qg][nf][0] - FMAX);
                float p1 = __expf(sacc[qg][nf][1] - FMAX);
                float p2 = __expf(sacc[qg][nf][2] - FMAX);
                float p3 = __expf(sacc[qg][nf][3] - FMAX);
                l_p[qg] += (p0 + p1) + (p2 + p3);
                uint2 pk;
                pk.x = (u32)f2bf(p0) | ((u32)f2bf(p1) << 16);
                pk.y = (u32)f2bf(p2) | ((u32)f2bf(p3) << 16);
                int c16 = (nf * 2 + (fk >> 1)) ^ ((prow >> 2) & 3);
                *(uint2*)&Ps[wave][prow * 32 + c16 * 8 + (fk & 1) * 4] = pk;
            }
        }
        // O += P V (K=32: single k-step)
        short8 pf[2];
#pragma unroll
        for (int qg = 0; qg < 2; ++qg)
            pf[qg] = *(const short8*)&Ps[wave][(qg * 16 + frow) * 32 + ((fk ^ ((frow >> 2) & 3)) * 8)];
#pragma unroll
        for (int nf8 = 0; nf8 < 8; ++nf8) {
            short8 vf = *(const short8*)&Vs[cur][(nf8 * 16 + frow) * 32 + ((fk ^ ((frow >> 2) & 3)) * 8)];
#pragma unroll
            for (int qg = 0; qg < 2; ++qg)
                o[qg][nf8] = __builtin_amdgcn_mfma_f32_16x16x32_bf16(pf[qg], vf, o[qg][nf8], 0, 0, 0);
        }
        __syncthreads();
        cur ^= 1;
    }
#undef STAGE

    // l: sum the 4 fk-group partials (lanes sharing frow)
#pragma unroll
    for (int qg = 0; qg < 2; ++qg) {
        l_p[qg] += __shfl_xor(l_p[qg], 16);
        l_p[qg] += __shfl_xor(l_p[qg], 32);
    }

#pragma unroll
    for (int qg = 0; qg < 2; ++qg)
#pragma unroll
        for (int i = 0; i < 4; ++i) {
            float rinv = 1.0f / __shfl(l_p[qg], fk * 4 + i);
            int srow = qb * 64 + wave * 32 + qg * 16 + fk * 4 + i;
#pragma unroll
            for (int nf8 = 0; nf8 < 8; ++nf8)
                out[(size_t)srow * DIMSZ + h * HDIM + nf8 * 16 + frow] = o[qg][nf8][i] * rinv;
        }
}

// ---------------- launch ----------------
extern "C" void kernel_launch(void* const* d_in, const int* in_sizes, int n_in,
                              void* d_out, int out_size, void* d_ws, size_t ws_size,
                              hipStream_t stream) {
    const float* hs = (const float*)d_in[0];
    const float* wq = (const float*)d_in[1];
    const float* bq = (const float*)d_in[2];
    const float* wk = (const float*)d_in[3];
    const float* bk = (const float*)d_in[4];
    const float* wv = (const float*)d_in[5];
    const float* bv = (const float*)d_in[6];
    const float* nq = (const float*)d_in[7];
    const float* nk = (const float*)d_in[8];
    const float* cosT = (const float*)d_in[9];
    const float* sinT = (const float*)d_in[10];
    float* out = (float*)d_out;

    char* ws = (char*)d_ws;
    u16* hs_b = (u16*)(ws);                      // 12,582,912
    u16* w_b = (u16*)(ws + 12582912);            // 56,623,104
    u16* qkv = (u16*)(ws + 69206016);            // 37,748,736
    u16* Qb = (u16*)(ws + 106954752);            // 12,582,912
    u16* Kb = (u16*)(ws + 119537664);            // 12,582,912
    u16* Vt = (u16*)(ws + 132120576);            // 12,582,912 -> total 144,703,488 B

    k_conv<<<dim3(33792), 256, 0, stream>>>((const float4*)hs, (const float4*)wq,
                                            (const float4*)wk, (const float4*)wv, hs_b, w_b);

    k_gemm<<<dim3(512), 256, 0, stream>>>(hs_b, w_b, qkv);

    k_post<<<dim3(3072), 256, 0, stream>>>(qkv, nq, nk, bq, bk, bv, cosT, sinT, Qb, Kb, Vt);

    // attention: 768 blocks = exactly 3/CU, 2 waves x 32 q-rows, KVBLK=32
    k_attn<<<dim3(768), 128, 0, stream>>>(Qb, Kb, Vt, out);
}